// Round 6
// baseline (367.314 us; speedup 1.0000x reference)
//
#include <hip/hip_runtime.h>
#include <hip/hip_fp16.h>
#include <math.h>

// GCN 3-layer, no inter-layer nonlinearity -> algebraic collapse:
//   out = sigmoid( A^3 (x @ Wc) + s2*c1 + s1*c2 + b3 )
//   Wc = W1@W2@W3, c1 = b1@W2@W3, c2 = b2@W3, s1 = A*1, s2 = A*s1
// CSR build: one global-atomic pass (rank capture), atomic-free fill.
// Aggregation: COLUMN-SPLIT. Cols 0-15 and 16-31 are independent through
// all three A-applications, so each 3-pass chain works on a 3.2 MB fp16
// half-table that fits a single XCD's 4 MB L2 -> random gathers become
// L2 hits instead of ~700cy L3 round-trips. All math fp32.

__device__ __forceinline__ int xcc_id() {
    int x;
    asm volatile("s_getreg_b32 %0, hwreg(HW_REG_XCC_ID)" : "=s"(x));
    return x & 7;
}

// ---------- zero histogram replicas ----------
__global__ void zero_hist_kernel(int4* __restrict__ hist, int n4) {
    int i = blockIdx.x * 256 + threadIdx.x;
    int stride = gridDim.x * 256;
    for (; i < n4; i += stride) hist[i] = make_int4(0, 0, 0, 0);
}

// ---------- count + rank: XCD-replicated bins, 4 edges/thread ----------
__global__ void count_rank_kernel(const int* __restrict__ ei, int* __restrict__ hist,
                                  int* __restrict__ rank, int N, int E) {
    int k = xcc_id();
    int* h = hist + (size_t)k * N;
    int base = blockIdx.x * 1024 + threadIdx.x;
    #pragma unroll
    for (int j = 0; j < 4; ++j) {
        int e = base + j * 256;
        if (e < E) {
            int c = ei[E + e];
            int r = __hip_atomic_fetch_add(&h[c], 1, __ATOMIC_RELAXED,
                                           __HIP_MEMORY_SCOPE_WORKGROUP);
            rank[e] = (r << 3) | k;
        }
    }
}

// ---------- scan: per-node replica prefixes + block-exclusive rowptr ----------
__global__ void scan_block_kernel(const int* __restrict__ hist, int* __restrict__ rowptr,
                                  int* __restrict__ bsums, ushort* __restrict__ relb,
                                  int N, int n) {
    __shared__ int s[256];
    int tid = threadIdx.x;
    int i = blockIdx.x * 256 + tid;
    int v = 0;
    ushort pk[8];
    if (i < n) {
        int p = 0;
        #pragma unroll
        for (int k = 0; k < 8; ++k) {
            pk[k] = (ushort)p;
            p += hist[(size_t)k * N + i];
        }
        v = p;
    }
    s[tid] = v;
    __syncthreads();
    for (int off = 1; off < 256; off <<= 1) {
        int t = (tid >= off) ? s[tid - off] : 0;
        __syncthreads();
        s[tid] += t;
        __syncthreads();
    }
    if (i < n) {
        rowptr[i] = s[tid] - v;
        ushort4 a = { pk[0], pk[1], pk[2], pk[3] };
        ushort4 b = { pk[4], pk[5], pk[6], pk[7] };
        *(ushort4*)&relb[(size_t)i * 8]     = a;
        *(ushort4*)&relb[(size_t)i * 8 + 4] = b;
    }
    if (tid == 255) bsums[blockIdx.x] = s[255];
}

__global__ void scan_bsums_kernel(int* __restrict__ bsums, int nb) {
    __shared__ int s[1024];
    int tid = threadIdx.x;
    int v = (tid < nb) ? bsums[tid] : 0;
    s[tid] = v;
    __syncthreads();
    for (int off = 1; off < 1024; off <<= 1) {
        int t = (tid >= off) ? s[tid - off] : 0;
        __syncthreads();
        s[tid] += t;
        __syncthreads();
    }
    if (tid < nb) bsums[tid] = s[tid] - v;
}

__global__ void scan_add_kernel(int* __restrict__ rowptr, const int* __restrict__ bsums,
                                int n, int E) {
    int i = blockIdx.x * 256 + threadIdx.x;
    if (i < n) rowptr[i] += bsums[i >> 8];
    if (i == n) rowptr[n] = E;
}

// ---------- fill CSR (atomic-free), 4 edges/thread ----------
__global__ void fill_kernel(const int* __restrict__ ei, const float* __restrict__ ew,
                            const int* __restrict__ rowptr, const int* __restrict__ rank,
                            const ushort* __restrict__ relb, int2* __restrict__ csr, int E) {
    int base = blockIdx.x * 1024 + threadIdx.x;
    #pragma unroll
    for (int j = 0; j < 4; ++j) {
        int e = base + j * 256;
        if (e < E) {
            int r = ei[e];
            int c = ei[E + e];
            int rv = rank[e];
            int k = rv & 7;
            int idx = rowptr[c] + (int)relb[((size_t)c << 3) | k] + (rv >> 3);
            csr[idx] = make_int2(r, __float_as_int(ew[e]));
        }
    }
}

// ---------- deg -> dinv from CSR ----------
__global__ void deg_kernel(const int* __restrict__ rowptr, const int2* __restrict__ csr,
                           float* __restrict__ dinv, int n) {
    int v = blockIdx.x * 256 + threadIdx.x;
    if (v >= n) return;
    float acc = 1.0f;
    int beg = rowptr[v], end = rowptr[v + 1];
    for (int i = beg; i < end; ++i) acc += __int_as_float(csr[i].y);
    dinv[v] = rsqrtf(acc);
}

// ---------- nrm finalize (in place) + s1 = A*1 ----------
__global__ void nrm_s1_kernel(const float* __restrict__ dinv, const int* __restrict__ rowptr,
                              int2* __restrict__ csr, float* __restrict__ s1, int n) {
    int v = blockIdx.x * 256 + threadIdx.x;
    if (v >= n) return;
    float dv = dinv[v];
    float acc = dv * dv;
    int beg = rowptr[v], end = rowptr[v + 1];
    for (int i = beg; i < end; ++i) {
        int2 rec = csr[i];
        float nm = dv * __int_as_float(rec.y) * dinv[rec.x];
        acc += nm;
        rec.y = __float_as_int(nm);
        csr[i] = rec;
    }
    s1[v] = acc;
}

// ---------- weight composition: Wc = W1@W2@W3, c1 = b1@W2@W3, c2 = b2@W3 ----------
__global__ __launch_bounds__(256) void compose_kernel(
    const float* __restrict__ W1, const float* __restrict__ b1,
    const float* __restrict__ W2, const float* __restrict__ b2,
    const float* __restrict__ W3, const float* __restrict__ b3,
    float* __restrict__ Wc, float* __restrict__ c1, float* __restrict__ c2) {
    __shared__ float sW2[128 * 64];
    __shared__ float sU[65 * 64];
    __shared__ float sW3[64 * 32];
    int tid = threadIdx.x;
    for (int i = tid * 4; i < 128 * 64; i += 1024) *(float4*)&sW2[i] = *(const float4*)&W2[i];
    for (int i = tid * 4; i < 64 * 32; i += 1024)  *(float4*)&sW3[i] = *(const float4*)&W3[i];
    __syncthreads();
    for (int o = tid; o < 65 * 64; o += 256) {
        int r = o >> 6, c = o & 63;
        const float* arow = (r < 64) ? &W1[r * 128] : b1;
        float acc = 0.f;
        #pragma unroll 8
        for (int k = 0; k < 128; ++k) acc += arow[k] * sW2[k * 64 + c];
        sU[o] = acc;
    }
    __syncthreads();
    for (int o = tid; o < 66 * 32; o += 256) {
        int r = o >> 5, c = o & 31;
        float acc = 0.f;
        if (r < 65) {
            const float* arow = &sU[r * 64];
            #pragma unroll 8
            for (int k = 0; k < 64; ++k) acc += arow[k] * sW3[k * 32 + c];
            if (r < 64) Wc[r * 32 + c] = acc; else c1[c] = acc;
        } else {
            #pragma unroll 8
            for (int k = 0; k < 64; ++k) acc += b2[k] * sW3[k * 32 + c];
            c2[c] = acc;
        }
    }
}

// ---------- GEMM: [n,64] @ [64,32] -> two fp16 half-tables [n,16] ----------
template <int K, int D>
__global__ __launch_bounds__(256) void gemm_kernel(const float* __restrict__ X,
                                                   const float* __restrict__ W,
                                                   __half* __restrict__ TA,
                                                   __half* __restrict__ TB, int n) {
    constexpr int NB = 64;
    __shared__ float sW[K * D];
    __shared__ float sX[NB * K];
    int tid = threadIdx.x;
    int base = blockIdx.x * NB;
    int nthis = n - base;
    if (nthis > NB) nthis = NB;

    for (int i = tid * 4; i < K * D; i += 256 * 4)
        *(float4*)&sW[i] = *(const float4*)&W[i];
    for (int i = tid * 4; i < nthis * K; i += 256 * 4)
        *(float4*)&sX[i] = *(const float4*)&X[(size_t)base * K + i];
    __syncthreads();

    constexpr int C4 = D / 4;
    constexpr int NG = 256 / C4;
    int c4 = tid % C4;
    int ng = tid / C4;
    for (int nl = ng; nl < nthis; nl += NG) {
        const float* xr = &sX[nl * K];
        float4 acc = {0.f, 0.f, 0.f, 0.f};
        #pragma unroll
        for (int k = 0; k < K; ++k) {
            float a = xr[k];
            float4 wv = *(const float4*)&sW[k * D + c4 * 4];
            acc.x += a * wv.x; acc.y += a * wv.y;
            acc.z += a * wv.z; acc.w += a * wv.w;
        }
        __half2 h0 = __floats2half2_rn(acc.x, acc.y);
        __half2 h1 = __floats2half2_rn(acc.z, acc.w);
        uint2 u = { *(unsigned*)&h0, *(unsigned*)&h1 };
        __half* dst = (c4 < 4) ? &TA[(size_t)(base + nl) * 16 + c4 * 4]
                               : &TB[(size_t)(base + nl) * 16 + (c4 - 4) * 4];
        *(uint2*)dst = u;
    }
}

// ---------- agg16: one A-application on a 16-col fp16 half-table ----------
// out[v] = ns*T[v] + sum nrm*T[src]; S2: also s2[v] = ns*s1[v] + sum nrm*s1[src]
// PHASE 2: epilogue += s2*c1o + s1*c2o + b3o, sigmoid, write fp32 out cols.
template <int PHASE, bool S2>
__global__ __launch_bounds__(256) void agg16_kernel(const __half* __restrict__ T,
                                                    const float* __restrict__ dinv,
                                                    const int* __restrict__ rowptr,
                                                    const int2* __restrict__ csr,
                                                    const float* __restrict__ s1,
                                                    float* __restrict__ s2,
                                                    const float* __restrict__ c1o,
                                                    const float* __restrict__ c2o,
                                                    const float* __restrict__ b3o,
                                                    void* __restrict__ outp,
                                                    int colOff, int n) {
    int l = threadIdx.x & 3;                         // 4 lanes x 4 halves = 16 cols
    int node = blockIdx.x * 64 + (threadIdx.x >> 2);
    if (node >= n) return;

    float di = dinv[node];
    float ns = di * di;
    uint2 tu = *(const uint2*)&T[(size_t)node * 16 + l * 4];
    float2 t0 = __half22float2(*(__half2*)&tu.x);
    float2 t1 = __half22float2(*(__half2*)&tu.y);
    float4 acc = { t0.x * ns, t0.y * ns, t1.x * ns, t1.y * ns };
    float sacc = S2 ? ns * s1[node] : 0.f;

    int beg = rowptr[node];
    int end = rowptr[node + 1];
    int i = beg;
    for (; i + 2 <= end; i += 2) {
        int2 r0 = csr[i];
        int2 r1 = csr[i + 1];
        uint2 g0 = *(const uint2*)&T[(size_t)r0.x * 16 + l * 4];
        uint2 g1 = *(const uint2*)&T[(size_t)r1.x * 16 + l * 4];
        float w0 = __int_as_float(r0.y);
        float w1 = __int_as_float(r1.y);
        float2 a0 = __half22float2(*(__half2*)&g0.x);
        float2 a1 = __half22float2(*(__half2*)&g0.y);
        float2 b0 = __half22float2(*(__half2*)&g1.x);
        float2 b1 = __half22float2(*(__half2*)&g1.y);
        acc.x += w0 * a0.x + w1 * b0.x;
        acc.y += w0 * a0.y + w1 * b0.y;
        acc.z += w0 * a1.x + w1 * b1.x;
        acc.w += w0 * a1.y + w1 * b1.y;
        if (S2) sacc += w0 * s1[r0.x] + w1 * s1[r1.x];
    }
    if (i < end) {
        int2 r0 = csr[i];
        uint2 g0 = *(const uint2*)&T[(size_t)r0.x * 16 + l * 4];
        float w0 = __int_as_float(r0.y);
        float2 a0 = __half22float2(*(__half2*)&g0.x);
        float2 a1 = __half22float2(*(__half2*)&g0.y);
        acc.x += w0 * a0.x;
        acc.y += w0 * a0.y;
        acc.z += w0 * a1.x;
        acc.w += w0 * a1.y;
        if (S2) sacc += w0 * s1[r0.x];
    }

    if (S2 && l == 0) s2[node] = sacc;

    if (PHASE == 2) {
        float a = s2[node], b = s1[node];
        float4 c1v = *(const float4*)&c1o[l * 4];
        float4 c2v = *(const float4*)&c2o[l * 4];
        float4 b3v = *(const float4*)&b3o[l * 4];
        acc.x += a * c1v.x + b * c2v.x + b3v.x;
        acc.y += a * c1v.y + b * c2v.y + b3v.y;
        acc.z += a * c1v.z + b * c2v.z + b3v.z;
        acc.w += a * c1v.w + b * c2v.w + b3v.w;
        acc.x = 1.f / (1.f + __expf(-acc.x));
        acc.y = 1.f / (1.f + __expf(-acc.y));
        acc.z = 1.f / (1.f + __expf(-acc.z));
        acc.w = 1.f / (1.f + __expf(-acc.w));
        *(float4*)&((float*)outp)[(size_t)node * 32 + colOff + l * 4] = acc;
    } else {
        __half2 h0 = __floats2half2_rn(acc.x, acc.y);
        __half2 h1 = __floats2half2_rn(acc.z, acc.w);
        uint2 u = { *(unsigned*)&h0, *(unsigned*)&h1 };
        *(uint2*)&((__half*)outp)[(size_t)node * 16 + l * 4] = u;
    }
}

extern "C" void kernel_launch(void* const* d_in, const int* in_sizes, int n_in,
                              void* d_out, int out_size, void* d_ws, size_t ws_size,
                              hipStream_t stream) {
    const float* x  = (const float*)d_in[0];
    const int*   ei = (const int*)d_in[1];      // [2, E]: row=ei[0:E], col=ei[E:2E]
    const float* ew = (const float*)d_in[2];
    const float* W1 = (const float*)d_in[3];
    const float* b1 = (const float*)d_in[4];
    const float* W2 = (const float*)d_in[5];
    const float* b2 = (const float*)d_in[6];
    const float* W3 = (const float*)d_in[7];
    const float* b3 = (const float*)d_in[8];
    float* out = (float*)d_out;

    const int N = in_sizes[0] / 64;
    const int E = in_sizes[2];

    auto a16 = [](size_t v) { return (v + 15) & ~(size_t)15; };
    char* p = (char*)d_ws;
    int*    hist   = (int*)p;    p += a16((size_t)N * 8 * 4);    // 8 XCD replicas
    int*    rank   = (int*)p;    p += a16((size_t)E * 4);        // (local<<3)|xcd
    int*    rowptr = (int*)p;    p += a16((size_t)(N + 1) * 4);
    int*    bsums  = (int*)p;    p += a16((size_t)1024 * 4);
    ushort* relb   = (ushort*)p; p += a16((size_t)N * 8 * 2);    // per-node replica prefix
    int2*   csr    = (int2*)p;   p += a16((size_t)E * 8);        // {src, w/nrm}
    float*  dinv   = (float*)p;  p += a16((size_t)N * 4);
    float*  s1     = (float*)p;  p += a16((size_t)N * 4);
    float*  s2     = (float*)p;  p += a16((size_t)N * 4);
    float*  Wc     = (float*)p;  p += a16((size_t)64 * 32 * 4);
    float*  c1     = (float*)p;  p += a16((size_t)32 * 4);
    float*  c2     = (float*)p;  p += a16((size_t)32 * 4);
    __half* yA     = (__half*)p; p += a16((size_t)N * 16 * 2);   // cols 0-15
    __half* yB     = (__half*)p; p += a16((size_t)N * 16 * 2);   // cols 16-31
    __half* zA     = (__half*)p; p += a16((size_t)N * 16 * 2);
    __half* zB     = (__half*)p; p += a16((size_t)N * 16 * 2);

    const int nbN  = (N + 255) / 256;
    const int nbE4 = (E + 1023) / 1024;

    // CSR build
    zero_hist_kernel<<<512, 256, 0, stream>>>((int4*)hist, N * 2);
    count_rank_kernel<<<nbE4, 256, 0, stream>>>(ei, hist, rank, N, E);
    scan_block_kernel<<<nbN, 256, 0, stream>>>(hist, rowptr, bsums, relb, N, N);
    scan_bsums_kernel<<<1, 1024, 0, stream>>>(bsums, nbN);
    scan_add_kernel<<<(N + 1 + 255) / 256, 256, 0, stream>>>(rowptr, bsums, N, E);
    fill_kernel<<<nbE4, 256, 0, stream>>>(ei, ew, rowptr, rank, relb, csr, E);

    // Normalization from CSR
    deg_kernel<<<nbN, 256, 0, stream>>>(rowptr, csr, dinv, N);
    nrm_s1_kernel<<<nbN, 256, 0, stream>>>(dinv, rowptr, csr, s1, N);

    // Collapsed weights + dense transform (two fp16 half-tables out)
    compose_kernel<<<1, 256, 0, stream>>>(W1, b1, W2, b2, W3, b3, Wc, c1, c2);
    gemm_kernel<64, 32><<<(N + 63) / 64, 256, 0, stream>>>(x, Wc, yA, yB, N);

    // Column-group chains: 3 passes on a 3.2 MB L2-resident half-table each.
    const int aggGrid = (N + 63) / 64;
    // Group A (cols 0-15), computes s2 in pass 0:
    agg16_kernel<0, true ><<<aggGrid, 256, 0, stream>>>(yA, dinv, rowptr, csr, s1, s2, c1, c2, b3, zA, 0, N);
    agg16_kernel<1, false><<<aggGrid, 256, 0, stream>>>(zA, dinv, rowptr, csr, s1, s2, c1, c2, b3, yA, 0, N);
    agg16_kernel<2, false><<<aggGrid, 256, 0, stream>>>(yA, dinv, rowptr, csr, s1, s2, c1, c2, b3, out, 0, N);
    // Group B (cols 16-31):
    agg16_kernel<0, false><<<aggGrid, 256, 0, stream>>>(yB, dinv, rowptr, csr, s1, s2, c1, c2, b3, zB, 16, N);
    agg16_kernel<1, false><<<aggGrid, 256, 0, stream>>>(zB, dinv, rowptr, csr, s1, s2, c1, c2, b3, yB, 16, N);
    agg16_kernel<2, false><<<aggGrid, 256, 0, stream>>>(yB, dinv, rowptr, csr, s1, s2,
                                                        c1 + 16, c2 + 16, b3 + 16, out, 16, N);
}

// Round 7
// 262.931 us; speedup vs baseline: 1.3970x; 1.3970x over previous
//
#include <hip/hip_runtime.h>
#include <hip/hip_fp16.h>
#include <math.h>

// GCN 3-layer, no inter-layer nonlinearity -> algebraic collapse:
//   out = sigmoid( A^3 (x @ Wc) + s2*c1 + s1*c2 + b3 )
//   Wc = W1@W2@W3, c1 = b1@W2@W3, c2 = b2@W3, s1 = A*1, s2 = A*s1
// CSR build: ZERO global atomics. Two-level LDS bucket (counting) sort:
//   1a: per-block LDS histogram over 256-node dest buckets
//   1b: hierarchical scan of the (bucket x block) matrix
//   1c: scatter edges bucket-ordered via LDS cursors
//   2:  per-bucket block: LDS per-node count + scan -> rowptr, csr, dinv
// Aggregation: 3 passes at D=32 on fp16 rows (64B = one line per gather).

#define EPB 4096   // edges per pass-1 block
#define MAXBKT 512 // >= ceil(N/256)

// ---------- 1a: per-block bucket histogram (LDS atomics only) ----------
__global__ __launch_bounds__(256) void hist1_kernel(const int* __restrict__ ei,
                                                    int* __restrict__ hist1,
                                                    int nbkt, int nblk1, int E) {
    __shared__ int lh[MAXBKT];
    int tid = threadIdx.x;
    for (int b = tid; b < nbkt; b += 256) lh[b] = 0;
    __syncthreads();
    int base = blockIdx.x * EPB;
    #pragma unroll
    for (int j = 0; j < EPB / 256; ++j) {
        int e = base + j * 256 + tid;
        if (e < E) atomicAdd(&lh[ei[E + e] >> 8], 1);
    }
    __syncthreads();
    for (int b = tid; b < nbkt; b += 256)
        hist1[(size_t)b * nblk1 + blockIdx.x] = lh[b];
}

// ---------- hierarchical exclusive scan (reused for bucket matrix) ----------
__global__ void scan_block_kernel(const int* __restrict__ counts, int* __restrict__ outp,
                                  int* __restrict__ bsums, int n) {
    __shared__ int s[256];
    int tid = threadIdx.x;
    int i = blockIdx.x * 256 + tid;
    int v = (i < n) ? counts[i] : 0;
    s[tid] = v;
    __syncthreads();
    for (int off = 1; off < 256; off <<= 1) {
        int t = (tid >= off) ? s[tid - off] : 0;
        __syncthreads();
        s[tid] += t;
        __syncthreads();
    }
    if (i < n) outp[i] = s[tid] - v;
    if (tid == 255) bsums[blockIdx.x] = s[255];
}

__global__ void scan_bsums_kernel(int* __restrict__ bsums, int nb) {
    __shared__ int s[1024];
    int tid = threadIdx.x;
    int v = (tid < nb) ? bsums[tid] : 0;
    s[tid] = v;
    __syncthreads();
    for (int off = 1; off < 1024; off <<= 1) {
        int t = (tid >= off) ? s[tid - off] : 0;
        __syncthreads();
        s[tid] += t;
        __syncthreads();
    }
    if (tid < nb) bsums[tid] = s[tid] - v;
}

__global__ void scan_add_kernel(int* __restrict__ outp, const int* __restrict__ bsums,
                                int n, int E) {
    int i = blockIdx.x * 256 + threadIdx.x;
    if (i < n) outp[i] += bsums[i >> 8];
    if (i == n) outp[n] = E;   // sentinel
}

// ---------- 1c: scatter edges to bucket-ordered tmp (LDS cursors) ----------
__global__ __launch_bounds__(256) void bucket_scatter_kernel(const int* __restrict__ ei,
                                                             const float* __restrict__ ew,
                                                             const int* __restrict__ scan1,
                                                             int2* __restrict__ tmp,
                                                             int nbkt, int nblk1, int E) {
    __shared__ int cur[MAXBKT];
    int tid = threadIdx.x;
    for (int b = tid; b < nbkt; b += 256)
        cur[b] = scan1[(size_t)b * nblk1 + blockIdx.x];
    __syncthreads();
    int base = blockIdx.x * EPB;
    #pragma unroll
    for (int j = 0; j < EPB / 256; ++j) {
        int e = base + j * 256 + tid;
        if (e < E) {
            int s = ei[e];
            int d = ei[E + e];
            float w = ew[e];
            int pos = atomicAdd(&cur[d >> 8], 1);
            tmp[pos] = make_int2(s | ((d & 255) << 20), __float_as_int(w));
        }
    }
}

// ---------- 2: per-bucket build: rowptr, csr, dinv (all LDS-local) ----------
__global__ __launch_bounds__(256) void bucket_build_kernel(const int* __restrict__ scan1,
                                                           const int2* __restrict__ tmp,
                                                           int* __restrict__ rowptr,
                                                           int2* __restrict__ csr,
                                                           float* __restrict__ dinv,
                                                           int nblk1, int N, int E) {
    __shared__ int s[256];
    __shared__ int cur[256];
    __shared__ float wsum[256];
    int b = blockIdx.x;
    int tid = threadIdx.x;
    int beg = scan1[(size_t)b * nblk1];
    int end = scan1[(size_t)(b + 1) * nblk1];   // sentinel covers last bucket

    s[tid] = 0;
    wsum[tid] = 0.f;
    __syncthreads();
    for (int i = beg + tid; i < end; i += 256) {
        int2 r = tmp[i];
        int dl = r.x >> 20;
        atomicAdd(&s[dl], 1);
        atomicAdd(&wsum[dl], __int_as_float(r.y));
    }
    __syncthreads();
    int myc = s[tid];
    for (int off = 1; off < 256; off <<= 1) {
        int t = (tid >= off) ? s[tid - off] : 0;
        __syncthreads();
        s[tid] += t;
        __syncthreads();
    }
    int excl = s[tid] - myc;
    cur[tid] = excl;
    int node = b * 256 + tid;
    if (node <= N) rowptr[node] = beg + excl;   // node==N lands exactly at E
    if (node < N)  dinv[node] = rsqrtf(1.0f + wsum[tid]);
    __syncthreads();
    for (int i = beg + tid; i < end; i += 256) {
        int2 r = tmp[i];
        int dl = r.x >> 20;
        int pos = beg + atomicAdd(&cur[dl], 1);
        csr[pos] = make_int2(r.x & 0xFFFFF, r.y);
    }
}

// ---------- nrm finalize (in place) + s1 = A*1 ----------
__global__ void nrm_s1_kernel(const float* __restrict__ dinv, const int* __restrict__ rowptr,
                              int2* __restrict__ csr, float* __restrict__ s1, int n) {
    int v = blockIdx.x * 256 + threadIdx.x;
    if (v >= n) return;
    float dv = dinv[v];
    float acc = dv * dv;
    int beg = rowptr[v], end = rowptr[v + 1];
    for (int i = beg; i < end; ++i) {
        int2 rec = csr[i];
        float nm = dv * __int_as_float(rec.y) * dinv[rec.x];
        acc += nm;
        rec.y = __float_as_int(nm);
        csr[i] = rec;
    }
    s1[v] = acc;
}

// ---------- weight composition: Wc = W1@W2@W3, c1 = b1@W2@W3, c2 = b2@W3 ----------
__global__ __launch_bounds__(256) void compose_kernel(
    const float* __restrict__ W1, const float* __restrict__ b1,
    const float* __restrict__ W2, const float* __restrict__ b2,
    const float* __restrict__ W3, const float* __restrict__ b3,
    float* __restrict__ Wc, float* __restrict__ c1, float* __restrict__ c2) {
    __shared__ float sW2[128 * 64];
    __shared__ float sU[65 * 64];
    __shared__ float sW3[64 * 32];
    int tid = threadIdx.x;
    for (int i = tid * 4; i < 128 * 64; i += 1024) *(float4*)&sW2[i] = *(const float4*)&W2[i];
    for (int i = tid * 4; i < 64 * 32; i += 1024)  *(float4*)&sW3[i] = *(const float4*)&W3[i];
    __syncthreads();
    for (int o = tid; o < 65 * 64; o += 256) {
        int r = o >> 6, c = o & 63;
        const float* arow = (r < 64) ? &W1[r * 128] : b1;
        float acc = 0.f;
        #pragma unroll 8
        for (int k = 0; k < 128; ++k) acc += arow[k] * sW2[k * 64 + c];
        sU[o] = acc;
    }
    __syncthreads();
    for (int o = tid; o < 66 * 32; o += 256) {
        int r = o >> 5, c = o & 31;
        float acc = 0.f;
        if (r < 65) {
            const float* arow = &sU[r * 64];
            #pragma unroll 8
            for (int k = 0; k < 64; ++k) acc += arow[k] * sW3[k * 32 + c];
            if (r < 64) Wc[r * 32 + c] = acc; else c1[c] = acc;
        } else {
            #pragma unroll 8
            for (int k = 0; k < 64; ++k) acc += b2[k] * sW3[k * 32 + c];
            c2[c] = acc;
        }
    }
}

// ---------- GEMM: T[n, 32] = X[n, 64] @ Wc[64, 32], output fp16 ----------
template <int K, int D>
__global__ __launch_bounds__(256) void gemm_kernel(const float* __restrict__ X,
                                                   const float* __restrict__ W,
                                                   __half* __restrict__ T, int n) {
    constexpr int NB = 64;
    __shared__ float sW[K * D];
    __shared__ float sX[NB * K];
    int tid = threadIdx.x;
    int base = blockIdx.x * NB;
    int nthis = n - base;
    if (nthis > NB) nthis = NB;

    for (int i = tid * 4; i < K * D; i += 256 * 4)
        *(float4*)&sW[i] = *(const float4*)&W[i];
    for (int i = tid * 4; i < nthis * K; i += 256 * 4)
        *(float4*)&sX[i] = *(const float4*)&X[(size_t)base * K + i];
    __syncthreads();

    constexpr int C4 = D / 4;
    constexpr int NG = 256 / C4;
    int c4 = tid % C4;
    int ng = tid / C4;
    for (int nl = ng; nl < nthis; nl += NG) {
        const float* xr = &sX[nl * K];
        float4 acc = {0.f, 0.f, 0.f, 0.f};
        #pragma unroll
        for (int k = 0; k < K; ++k) {
            float a = xr[k];
            float4 wv = *(const float4*)&sW[k * D + c4 * 4];
            acc.x += a * wv.x; acc.y += a * wv.y;
            acc.z += a * wv.z; acc.w += a * wv.w;
        }
        __half2 h0 = __floats2half2_rn(acc.x, acc.y);
        __half2 h1 = __floats2half2_rn(acc.z, acc.w);
        uint2 u = { *(unsigned*)&h0, *(unsigned*)&h1 };
        *(uint2*)&T[(size_t)(base + nl) * D + c4 * 4] = u;
    }
}

// ---------- agg32 on fp16 rows ----------
template <int PHASE>
__global__ __launch_bounds__(256) void agg32_kernel(const __half* __restrict__ T,
                                                    const float* __restrict__ dinv,
                                                    const int* __restrict__ rowptr,
                                                    const int2* __restrict__ csr,
                                                    const float* __restrict__ s1,
                                                    float* __restrict__ s2,
                                                    const float* __restrict__ c1,
                                                    const float* __restrict__ c2,
                                                    const float* __restrict__ b3,
                                                    void* __restrict__ outp, int n) {
    int c4 = threadIdx.x & 7;                       // 8 lanes x 4 halves = 32 cols
    int node = blockIdx.x * 32 + (threadIdx.x >> 3);
    if (node >= n) return;

    float di = dinv[node];
    float ns = di * di;
    uint2 tu = *(const uint2*)&T[(size_t)node * 32 + c4 * 4];
    float2 t0 = __half22float2(*(__half2*)&tu.x);
    float2 t1 = __half22float2(*(__half2*)&tu.y);
    float4 acc = { t0.x * ns, t0.y * ns, t1.x * ns, t1.y * ns };
    float sacc = (PHASE == 0) ? ns * s1[node] : 0.f;

    int beg = rowptr[node];
    int end = rowptr[node + 1];
    int i = beg;
    for (; i + 2 <= end; i += 2) {
        int2 r0 = csr[i];
        int2 r1 = csr[i + 1];
        uint2 g0 = *(const uint2*)&T[(size_t)r0.x * 32 + c4 * 4];
        uint2 g1 = *(const uint2*)&T[(size_t)r1.x * 32 + c4 * 4];
        float w0 = __int_as_float(r0.y);
        float w1 = __int_as_float(r1.y);
        float2 a0 = __half22float2(*(__half2*)&g0.x);
        float2 a1 = __half22float2(*(__half2*)&g0.y);
        float2 b0 = __half22float2(*(__half2*)&g1.x);
        float2 b1 = __half22float2(*(__half2*)&g1.y);
        acc.x += w0 * a0.x + w1 * b0.x;
        acc.y += w0 * a0.y + w1 * b0.y;
        acc.z += w0 * a1.x + w1 * b1.x;
        acc.w += w0 * a1.y + w1 * b1.y;
        if (PHASE == 0) sacc += w0 * s1[r0.x] + w1 * s1[r1.x];
    }
    if (i < end) {
        int2 r0 = csr[i];
        uint2 g0 = *(const uint2*)&T[(size_t)r0.x * 32 + c4 * 4];
        float w0 = __int_as_float(r0.y);
        float2 a0 = __half22float2(*(__half2*)&g0.x);
        float2 a1 = __half22float2(*(__half2*)&g0.y);
        acc.x += w0 * a0.x;
        acc.y += w0 * a0.y;
        acc.z += w0 * a1.x;
        acc.w += w0 * a1.y;
        if (PHASE == 0) sacc += w0 * s1[r0.x];
    }

    if (PHASE == 0 && c4 == 0) s2[node] = sacc;

    if (PHASE == 2) {
        float a = s2[node], b = s1[node];
        float4 c1v = *(const float4*)&c1[c4 * 4];
        float4 c2v = *(const float4*)&c2[c4 * 4];
        float4 b3v = *(const float4*)&b3[c4 * 4];
        acc.x += a * c1v.x + b * c2v.x + b3v.x;
        acc.y += a * c1v.y + b * c2v.y + b3v.y;
        acc.z += a * c1v.z + b * c2v.z + b3v.z;
        acc.w += a * c1v.w + b * c2v.w + b3v.w;
        acc.x = 1.f / (1.f + __expf(-acc.x));
        acc.y = 1.f / (1.f + __expf(-acc.y));
        acc.z = 1.f / (1.f + __expf(-acc.z));
        acc.w = 1.f / (1.f + __expf(-acc.w));
        *(float4*)&((float*)outp)[(size_t)node * 32 + c4 * 4] = acc;
    } else {
        __half2 h0 = __floats2half2_rn(acc.x, acc.y);
        __half2 h1 = __floats2half2_rn(acc.z, acc.w);
        uint2 u = { *(unsigned*)&h0, *(unsigned*)&h1 };
        *(uint2*)&((__half*)outp)[(size_t)node * 32 + c4 * 4] = u;
    }
}

extern "C" void kernel_launch(void* const* d_in, const int* in_sizes, int n_in,
                              void* d_out, int out_size, void* d_ws, size_t ws_size,
                              hipStream_t stream) {
    const float* x  = (const float*)d_in[0];
    const int*   ei = (const int*)d_in[1];      // [2, E]: row=ei[0:E], col=ei[E:2E]
    const float* ew = (const float*)d_in[2];
    const float* W1 = (const float*)d_in[3];
    const float* b1 = (const float*)d_in[4];
    const float* W2 = (const float*)d_in[5];
    const float* b2 = (const float*)d_in[6];
    const float* W3 = (const float*)d_in[7];
    const float* b3 = (const float*)d_in[8];
    float* out = (float*)d_out;

    const int N = in_sizes[0] / 64;
    const int E = in_sizes[2];

    const int nbkt  = (N + 255) >> 8;            // 391
    const int nblk1 = (E + EPB - 1) / EPB;       // 391 @ EPB=4096
    const int nscan = nbkt * nblk1;              // 152,881

    auto a16 = [](size_t v) { return (v + 15) & ~(size_t)15; };
    char* p = (char*)d_ws;
    int*    hist1  = (int*)p;    p += a16((size_t)nscan * 4);
    int*    scan1  = (int*)p;    p += a16((size_t)(nscan + 1) * 4);
    int*    bsums  = (int*)p;    p += a16((size_t)1024 * 4);
    int2*   tmp    = (int2*)p;   p += a16((size_t)E * 8);        // bucket-ordered edges
    int*    rowptr = (int*)p;    p += a16((size_t)(N + 1) * 4);
    int2*   csr    = (int2*)p;   p += a16((size_t)E * 8);        // {src, w/nrm}
    float*  dinv   = (float*)p;  p += a16((size_t)N * 4);
    float*  s1     = (float*)p;  p += a16((size_t)N * 4);
    float*  s2     = (float*)p;  p += a16((size_t)N * 4);
    float*  Wc     = (float*)p;  p += a16((size_t)64 * 32 * 4);
    float*  c1     = (float*)p;  p += a16((size_t)32 * 4);
    float*  c2     = (float*)p;  p += a16((size_t)32 * 4);
    __half* y      = (__half*)p; p += a16((size_t)N * 32 * 2);
    __half* z      = (__half*)p; p += a16((size_t)N * 32 * 2);

    const int nbN = (N + 255) / 256;
    const int scanBlocks = (nscan + 255) / 256;  // 598 <= 1024

    // CSR build: LDS bucket sort, zero global atomics
    hist1_kernel<<<nblk1, 256, 0, stream>>>(ei, hist1, nbkt, nblk1, E);
    scan_block_kernel<<<scanBlocks, 256, 0, stream>>>(hist1, scan1, bsums, nscan);
    scan_bsums_kernel<<<1, 1024, 0, stream>>>(bsums, scanBlocks);
    scan_add_kernel<<<(nscan + 1 + 255) / 256, 256, 0, stream>>>(scan1, bsums, nscan, E);
    bucket_scatter_kernel<<<nblk1, 256, 0, stream>>>(ei, ew, scan1, tmp, nbkt, nblk1, E);
    bucket_build_kernel<<<nbkt, 256, 0, stream>>>(scan1, tmp, rowptr, csr, dinv, nblk1, N, E);

    // Normalization from CSR
    nrm_s1_kernel<<<nbN, 256, 0, stream>>>(dinv, rowptr, csr, s1, N);

    // Collapsed weights + dense transform (fp16 rows out)
    compose_kernel<<<1, 256, 0, stream>>>(W1, b1, W2, b2, W3, b3, Wc, c1, c2);
    gemm_kernel<64, 32><<<(N + 63) / 64, 256, 0, stream>>>(x, Wc, y, N);

    // Three sparse passes at D=32 on fp16 rows
    const int aggGrid = (N + 31) / 32;
    agg32_kernel<0><<<aggGrid, 256, 0, stream>>>(y, dinv, rowptr, csr, s1, s2, c1, c2, b3, z, N);
    agg32_kernel<1><<<aggGrid, 256, 0, stream>>>(z, dinv, rowptr, csr, s1, s2, c1, c2, b3, y, N);
    agg32_kernel<2><<<aggGrid, 256, 0, stream>>>(y, dinv, rowptr, csr, s1, s2, c1, c2, b3, out, N);
}

// Round 8
// 213.541 us; speedup vs baseline: 1.7201x; 1.2313x over previous
//
#include <hip/hip_runtime.h>
#include <hip/hip_fp16.h>
#include <math.h>

// GCN 3-layer, no inter-layer nonlinearity -> algebraic collapse:
//   out = sigmoid( A^3 (x @ Wc) + s2*c1 + s1*c2 + b3 )
//   Wc = W1@W2@W3, c1 = b1@W2@W3, c2 = b2@W3, s1 = A*1, s2 = A*s1
// CSR build: ZERO global atomics (two-level LDS bucket sort).
// Weight composition: row-parallel two-stage (65 + 66 blocks) instead of
// a single-block kernel (was 50us at 0.04% occupancy).
// Aggregation: 3 passes at D=32 on fp16 rows, 4 gathers in flight.

#define EPB 4096   // edges per pass-1 block
#define MAXBKT 512 // >= ceil(N/256)

// ---------- 1a: per-block bucket histogram (LDS atomics only) ----------
__global__ __launch_bounds__(256) void hist1_kernel(const int* __restrict__ ei,
                                                    int* __restrict__ hist1,
                                                    int nbkt, int nblk1, int E) {
    __shared__ int lh[MAXBKT];
    int tid = threadIdx.x;
    for (int b = tid; b < nbkt; b += 256) lh[b] = 0;
    __syncthreads();
    int base = blockIdx.x * EPB;
    #pragma unroll
    for (int j = 0; j < EPB / 256; ++j) {
        int e = base + j * 256 + tid;
        if (e < E) atomicAdd(&lh[ei[E + e] >> 8], 1);
    }
    __syncthreads();
    for (int b = tid; b < nbkt; b += 256)
        hist1[(size_t)b * nblk1 + blockIdx.x] = lh[b];
}

// ---------- hierarchical exclusive scan ----------
__global__ void scan_block_kernel(const int* __restrict__ counts, int* __restrict__ outp,
                                  int* __restrict__ bsums, int n) {
    __shared__ int s[256];
    int tid = threadIdx.x;
    int i = blockIdx.x * 256 + tid;
    int v = (i < n) ? counts[i] : 0;
    s[tid] = v;
    __syncthreads();
    for (int off = 1; off < 256; off <<= 1) {
        int t = (tid >= off) ? s[tid - off] : 0;
        __syncthreads();
        s[tid] += t;
        __syncthreads();
    }
    if (i < n) outp[i] = s[tid] - v;
    if (tid == 255) bsums[blockIdx.x] = s[255];
}

__global__ void scan_bsums_kernel(int* __restrict__ bsums, int nb) {
    __shared__ int s[1024];
    int tid = threadIdx.x;
    int v = (tid < nb) ? bsums[tid] : 0;
    s[tid] = v;
    __syncthreads();
    for (int off = 1; off < 1024; off <<= 1) {
        int t = (tid >= off) ? s[tid - off] : 0;
        __syncthreads();
        s[tid] += t;
        __syncthreads();
    }
    if (tid < nb) bsums[tid] = s[tid] - v;
}

__global__ void scan_add_kernel(int* __restrict__ outp, const int* __restrict__ bsums,
                                int n, int E) {
    int i = blockIdx.x * 256 + threadIdx.x;
    if (i < n) outp[i] += bsums[i >> 8];
    if (i == n) outp[n] = E;   // sentinel
}

// ---------- 1c: scatter edges to bucket-ordered tmp (LDS cursors) ----------
__global__ __launch_bounds__(256) void bucket_scatter_kernel(const int* __restrict__ ei,
                                                             const float* __restrict__ ew,
                                                             const int* __restrict__ scan1,
                                                             int2* __restrict__ tmp,
                                                             int nbkt, int nblk1, int E) {
    __shared__ int cur[MAXBKT];
    int tid = threadIdx.x;
    for (int b = tid; b < nbkt; b += 256)
        cur[b] = scan1[(size_t)b * nblk1 + blockIdx.x];
    __syncthreads();
    int base = blockIdx.x * EPB;
    #pragma unroll
    for (int j = 0; j < EPB / 256; ++j) {
        int e = base + j * 256 + tid;
        if (e < E) {
            int s = ei[e];
            int d = ei[E + e];
            float w = ew[e];
            int pos = atomicAdd(&cur[d >> 8], 1);
            tmp[pos] = make_int2(s | ((d & 255) << 20), __float_as_int(w));
        }
    }
}

// ---------- 2: per-bucket build: rowptr, csr, dinv (all LDS-local) ----------
__global__ __launch_bounds__(256) void bucket_build_kernel(const int* __restrict__ scan1,
                                                           const int2* __restrict__ tmp,
                                                           int* __restrict__ rowptr,
                                                           int2* __restrict__ csr,
                                                           float* __restrict__ dinv,
                                                           int nblk1, int N, int E) {
    __shared__ int s[256];
    __shared__ int cur[256];
    __shared__ float wsum[256];
    int b = blockIdx.x;
    int tid = threadIdx.x;
    int beg = scan1[(size_t)b * nblk1];
    int end = scan1[(size_t)(b + 1) * nblk1];

    s[tid] = 0;
    wsum[tid] = 0.f;
    __syncthreads();
    for (int i = beg + tid; i < end; i += 256) {
        int2 r = tmp[i];
        int dl = r.x >> 20;
        atomicAdd(&s[dl], 1);
        atomicAdd(&wsum[dl], __int_as_float(r.y));
    }
    __syncthreads();
    int myc = s[tid];
    for (int off = 1; off < 256; off <<= 1) {
        int t = (tid >= off) ? s[tid - off] : 0;
        __syncthreads();
        s[tid] += t;
        __syncthreads();
    }
    int excl = s[tid] - myc;
    cur[tid] = excl;
    int node = b * 256 + tid;
    if (node <= N) rowptr[node] = beg + excl;
    if (node < N)  dinv[node] = rsqrtf(1.0f + wsum[tid]);
    __syncthreads();
    for (int i = beg + tid; i < end; i += 256) {
        int2 r = tmp[i];
        int dl = r.x >> 20;
        int pos = beg + atomicAdd(&cur[dl], 1);
        csr[pos] = make_int2(r.x & 0xFFFFF, r.y);
    }
}

// ---------- nrm finalize (in place) + s1 = A*1 ----------
__global__ void nrm_s1_kernel(const float* __restrict__ dinv, const int* __restrict__ rowptr,
                              int2* __restrict__ csr, float* __restrict__ s1, int n) {
    int v = blockIdx.x * 256 + threadIdx.x;
    if (v >= n) return;
    float dv = dinv[v];
    float acc = dv * dv;
    int beg = rowptr[v], end = rowptr[v + 1];
    for (int i = beg; i < end; ++i) {
        int2 rec = csr[i];
        float nm = dv * __int_as_float(rec.y) * dinv[rec.x];
        acc += nm;
        rec.y = __float_as_int(nm);
        csr[i] = rec;
    }
    s1[v] = acc;
}

// ---------- compose1: U = [W1;b1] @ W2  (65 rows x 64 cols, K=128) ----------
__global__ __launch_bounds__(256) void compose1_kernel(const float* __restrict__ W1,
                                                       const float* __restrict__ b1,
                                                       const float* __restrict__ W2,
                                                       float* __restrict__ U) {
    __shared__ float s[256];
    int r = blockIdx.x;                 // 0..64
    int tid = threadIdx.x;
    int c = tid & 63;
    int q = tid >> 6;                   // 0..3, k-chunk of 32
    const float* arow = (r < 64) ? &W1[r * 128] : b1;
    float acc = 0.f;
    #pragma unroll 8
    for (int k = q * 32; k < q * 32 + 32; ++k)
        acc += arow[k] * W2[k * 64 + c];
    s[tid] = acc;
    __syncthreads();
    if (q == 0)
        U[r * 64 + c] = s[c] + s[c + 64] + s[c + 128] + s[c + 192];
}

// ---------- compose2: rows of U @ W3 -> Wc, c1; b2 @ W3 -> c2 (K=64) ----------
__global__ __launch_bounds__(256) void compose2_kernel(const float* __restrict__ U,
                                                       const float* __restrict__ b2,
                                                       const float* __restrict__ W3,
                                                       float* __restrict__ Wc,
                                                       float* __restrict__ c1,
                                                       float* __restrict__ c2) {
    __shared__ float s[256];
    int r = blockIdx.x;                 // 0..65
    int tid = threadIdx.x;
    int c = tid & 31;
    int o = tid >> 5;                   // 0..7, k-chunk of 8
    const float* arow = (r < 65) ? &U[r * 64] : b2;
    float acc = 0.f;
    #pragma unroll
    for (int k = o * 8; k < o * 8 + 8; ++k)
        acc += arow[k] * W3[k * 32 + c];
    s[tid] = acc;
    __syncthreads();
    if (o == 0) {
        float v = 0.f;
        #pragma unroll
        for (int j = 0; j < 8; ++j) v += s[c + j * 32];
        if (r < 64) Wc[r * 32 + c] = v;
        else if (r == 64) c1[c] = v;
        else c2[c] = v;
    }
}

// ---------- GEMM: T[n, 32] = X[n, 64] @ Wc[64, 32], output fp16 ----------
template <int K, int D>
__global__ __launch_bounds__(256) void gemm_kernel(const float* __restrict__ X,
                                                   const float* __restrict__ W,
                                                   __half* __restrict__ T, int n) {
    constexpr int NB = 64;
    __shared__ float sW[K * D];
    __shared__ float sX[NB * K];
    int tid = threadIdx.x;
    int base = blockIdx.x * NB;
    int nthis = n - base;
    if (nthis > NB) nthis = NB;

    for (int i = tid * 4; i < K * D; i += 256 * 4)
        *(float4*)&sW[i] = *(const float4*)&W[i];
    for (int i = tid * 4; i < nthis * K; i += 256 * 4)
        *(float4*)&sX[i] = *(const float4*)&X[(size_t)base * K + i];
    __syncthreads();

    constexpr int C4 = D / 4;
    constexpr int NG = 256 / C4;
    int c4 = tid % C4;
    int ng = tid / C4;
    for (int nl = ng; nl < nthis; nl += NG) {
        const float* xr = &sX[nl * K];
        float4 acc = {0.f, 0.f, 0.f, 0.f};
        #pragma unroll
        for (int k = 0; k < K; ++k) {
            float a = xr[k];
            float4 wv = *(const float4*)&sW[k * D + c4 * 4];
            acc.x += a * wv.x; acc.y += a * wv.y;
            acc.z += a * wv.z; acc.w += a * wv.w;
        }
        __half2 h0 = __floats2half2_rn(acc.x, acc.y);
        __half2 h1 = __floats2half2_rn(acc.z, acc.w);
        uint2 u = { *(unsigned*)&h0, *(unsigned*)&h1 };
        *(uint2*)&T[(size_t)(base + nl) * D + c4 * 4] = u;
    }
}

// ---------- agg32 on fp16 rows, 4 gathers in flight ----------
template <int PHASE>
__global__ __launch_bounds__(256) void agg32_kernel(const __half* __restrict__ T,
                                                    const float* __restrict__ dinv,
                                                    const int* __restrict__ rowptr,
                                                    const int2* __restrict__ csr,
                                                    const float* __restrict__ s1,
                                                    float* __restrict__ s2,
                                                    const float* __restrict__ c1,
                                                    const float* __restrict__ c2,
                                                    const float* __restrict__ b3,
                                                    void* __restrict__ outp, int n) {
    int c4 = threadIdx.x & 7;                       // 8 lanes x 4 halves = 32 cols
    int node = blockIdx.x * 32 + (threadIdx.x >> 3);
    if (node >= n) return;

    float di = dinv[node];
    float ns = di * di;
    uint2 tu = *(const uint2*)&T[(size_t)node * 32 + c4 * 4];
    float2 t0 = __half22float2(*(__half2*)&tu.x);
    float2 t1 = __half22float2(*(__half2*)&tu.y);
    float4 acc = { t0.x * ns, t0.y * ns, t1.x * ns, t1.y * ns };
    float sacc = (PHASE == 0) ? ns * s1[node] : 0.f;

    int beg = rowptr[node];
    int end = rowptr[node + 1];
    int i = beg;
    for (; i + 4 <= end; i += 4) {
        int2 r0 = csr[i];
        int2 r1 = csr[i + 1];
        int2 r2 = csr[i + 2];
        int2 r3 = csr[i + 3];
        uint2 g0 = *(const uint2*)&T[(size_t)r0.x * 32 + c4 * 4];
        uint2 g1 = *(const uint2*)&T[(size_t)r1.x * 32 + c4 * 4];
        uint2 g2 = *(const uint2*)&T[(size_t)r2.x * 32 + c4 * 4];
        uint2 g3 = *(const uint2*)&T[(size_t)r3.x * 32 + c4 * 4];
        float w0 = __int_as_float(r0.y);
        float w1 = __int_as_float(r1.y);
        float w2 = __int_as_float(r2.y);
        float w3 = __int_as_float(r3.y);
        float2 a0 = __half22float2(*(__half2*)&g0.x);
        float2 a1 = __half22float2(*(__half2*)&g0.y);
        float2 b0 = __half22float2(*(__half2*)&g1.x);
        float2 b1 = __half22float2(*(__half2*)&g1.y);
        float2 e0 = __half22float2(*(__half2*)&g2.x);
        float2 e1 = __half22float2(*(__half2*)&g2.y);
        float2 f0 = __half22float2(*(__half2*)&g3.x);
        float2 f1 = __half22float2(*(__half2*)&g3.y);
        acc.x += w0 * a0.x + w1 * b0.x + w2 * e0.x + w3 * f0.x;
        acc.y += w0 * a0.y + w1 * b0.y + w2 * e0.y + w3 * f0.y;
        acc.z += w0 * a1.x + w1 * b1.x + w2 * e1.x + w3 * f1.x;
        acc.w += w0 * a1.y + w1 * b1.y + w2 * e1.y + w3 * f1.y;
        if (PHASE == 0) sacc += w0 * s1[r0.x] + w1 * s1[r1.x] + w2 * s1[r2.x] + w3 * s1[r3.x];
    }
    for (; i < end; ++i) {
        int2 r0 = csr[i];
        uint2 g0 = *(const uint2*)&T[(size_t)r0.x * 32 + c4 * 4];
        float w0 = __int_as_float(r0.y);
        float2 a0 = __half22float2(*(__half2*)&g0.x);
        float2 a1 = __half22float2(*(__half2*)&g0.y);
        acc.x += w0 * a0.x;
        acc.y += w0 * a0.y;
        acc.z += w0 * a1.x;
        acc.w += w0 * a1.y;
        if (PHASE == 0) sacc += w0 * s1[r0.x];
    }

    if (PHASE == 0 && c4 == 0) s2[node] = sacc;

    if (PHASE == 2) {
        float a = s2[node], b = s1[node];
        float4 c1v = *(const float4*)&c1[c4 * 4];
        float4 c2v = *(const float4*)&c2[c4 * 4];
        float4 b3v = *(const float4*)&b3[c4 * 4];
        acc.x += a * c1v.x + b * c2v.x + b3v.x;
        acc.y += a * c1v.y + b * c2v.y + b3v.y;
        acc.z += a * c1v.z + b * c2v.z + b3v.z;
        acc.w += a * c1v.w + b * c2v.w + b3v.w;
        acc.x = 1.f / (1.f + __expf(-acc.x));
        acc.y = 1.f / (1.f + __expf(-acc.y));
        acc.z = 1.f / (1.f + __expf(-acc.z));
        acc.w = 1.f / (1.f + __expf(-acc.w));
        *(float4*)&((float*)outp)[(size_t)node * 32 + c4 * 4] = acc;
    } else {
        __half2 h0 = __floats2half2_rn(acc.x, acc.y);
        __half2 h1 = __floats2half2_rn(acc.z, acc.w);
        uint2 u = { *(unsigned*)&h0, *(unsigned*)&h1 };
        *(uint2*)&((__half*)outp)[(size_t)node * 32 + c4 * 4] = u;
    }
}

extern "C" void kernel_launch(void* const* d_in, const int* in_sizes, int n_in,
                              void* d_out, int out_size, void* d_ws, size_t ws_size,
                              hipStream_t stream) {
    const float* x  = (const float*)d_in[0];
    const int*   ei = (const int*)d_in[1];      // [2, E]: row=ei[0:E], col=ei[E:2E]
    const float* ew = (const float*)d_in[2];
    const float* W1 = (const float*)d_in[3];
    const float* b1 = (const float*)d_in[4];
    const float* W2 = (const float*)d_in[5];
    const float* b2 = (const float*)d_in[6];
    const float* W3 = (const float*)d_in[7];
    const float* b3 = (const float*)d_in[8];
    float* out = (float*)d_out;

    const int N = in_sizes[0] / 64;
    const int E = in_sizes[2];

    const int nbkt  = (N + 255) >> 8;
    const int nblk1 = (E + EPB - 1) / EPB;
    const int nscan = nbkt * nblk1;

    auto a16 = [](size_t v) { return (v + 15) & ~(size_t)15; };
    char* p = (char*)d_ws;
    int*    hist1  = (int*)p;    p += a16((size_t)nscan * 4);
    int*    scan1  = (int*)p;    p += a16((size_t)(nscan + 1) * 4);
    int*    bsums  = (int*)p;    p += a16((size_t)1024 * 4);
    int2*   tmp    = (int2*)p;   p += a16((size_t)E * 8);
    int*    rowptr = (int*)p;    p += a16((size_t)(N + 1) * 4);
    int2*   csr    = (int2*)p;   p += a16((size_t)E * 8);
    float*  dinv   = (float*)p;  p += a16((size_t)N * 4);
    float*  s1     = (float*)p;  p += a16((size_t)N * 4);
    float*  s2     = (float*)p;  p += a16((size_t)N * 4);
    float*  Uc     = (float*)p;  p += a16((size_t)65 * 64 * 4);
    float*  Wc     = (float*)p;  p += a16((size_t)64 * 32 * 4);
    float*  c1     = (float*)p;  p += a16((size_t)32 * 4);
    float*  c2     = (float*)p;  p += a16((size_t)32 * 4);
    __half* y      = (__half*)p; p += a16((size_t)N * 32 * 2);
    __half* z      = (__half*)p; p += a16((size_t)N * 32 * 2);

    const int nbN = (N + 255) / 256;
    const int scanBlocks = (nscan + 255) / 256;

    // CSR build: LDS bucket sort, zero global atomics
    hist1_kernel<<<nblk1, 256, 0, stream>>>(ei, hist1, nbkt, nblk1, E);
    scan_block_kernel<<<scanBlocks, 256, 0, stream>>>(hist1, scan1, bsums, nscan);
    scan_bsums_kernel<<<1, 1024, 0, stream>>>(bsums, scanBlocks);
    scan_add_kernel<<<(nscan + 1 + 255) / 256, 256, 0, stream>>>(scan1, bsums, nscan, E);
    bucket_scatter_kernel<<<nblk1, 256, 0, stream>>>(ei, ew, scan1, tmp, nbkt, nblk1, E);
    bucket_build_kernel<<<nbkt, 256, 0, stream>>>(scan1, tmp, rowptr, csr, dinv, nblk1, N, E);

    // Normalization from CSR
    nrm_s1_kernel<<<nbN, 256, 0, stream>>>(dinv, rowptr, csr, s1, N);

    // Collapsed weights (row-parallel) + dense transform (fp16 rows out)
    compose1_kernel<<<65, 256, 0, stream>>>(W1, b1, W2, Uc);
    compose2_kernel<<<66, 256, 0, stream>>>(Uc, b2, W3, Wc, c1, c2);
    gemm_kernel<64, 32><<<(N + 63) / 64, 256, 0, stream>>>(x, Wc, y, N);

    // Three sparse passes at D=32 on fp16 rows
    const int aggGrid = (N + 31) / 32;
    agg32_kernel<0><<<aggGrid, 256, 0, stream>>>(y, dinv, rowptr, csr, s1, s2, c1, c2, b3, z, N);
    agg32_kernel<1><<<aggGrid, 256, 0, stream>>>(z, dinv, rowptr, csr, s1, s2, c1, c2, b3, y, N);
    agg32_kernel<2><<<aggGrid, 256, 0, stream>>>(y, dinv, rowptr, csr, s1, s2, c1, c2, b3, out, N);
}